// Round 1
// baseline (101.251 us; speedup 1.0000x reference)
//
#include <hip/hip_runtime.h>

// CapsLayer2D fused kernel.
// dims: B*R*C = 1024 ("brc"), I=128 input caps, DIN=16, K=32 output caps, DOUT=16.
// inputs: [brc, 128, 16] f32; W: [32, 128, 16, 16] f32; out: [brc, 32, 16] f32.
//
// One block (256 thr / 4 waves) handles one k and 8 brc (2 per wave).
// W[k] is staged through LDS in 4 chunks of 32 i (32KB each, padded stride).
// Each lane: i_loc = lane&31 (4 i's across chunks), o_half = lane>>5 (8 o's).
// res[2 brc][4 i][8 o] lives in registers; routing is done with wave shuffles
// using the identity that b never needs materializing beyond 4 scalars/lane.

constexpr int I_CAPS  = 128;
constexpr int DIN     = 16;
constexpr int DOUT    = 16;
constexpr int KCAPS   = 32;
constexpr int WSTRIDE = 260;   // 256 + 4 floats pad -> bank = (4*il + ...) % 32

__global__ __launch_bounds__(256)
void caps_fused(const float* __restrict__ x,
                const float* __restrict__ W,
                float* __restrict__ out)
{
    __shared__ float wlds[32 * WSTRIDE];   // 33,280 B

    const int tid  = threadIdx.x;
    const int lane = tid & 63;
    const int wave = tid >> 6;

    // supertile swizzle: groups of (8 k x 16 tiles) share W and x in L2
    const int b    = blockIdx.x;
    const int tq   = b & 15;
    const int kq   = (b >> 4) & 7;
    const int sg   = b >> 7;          // 32 supergroups
    const int k    = (sg & 3) * 8 + kq;
    const int tile = (sg >> 2) * 16 + tq;

    const int brc0 = tile * 8 + wave * 2;   // this wave's 2 brc

    const int il = lane & 31;   // i_loc within a 32-i chunk
    const int oh = lane >> 5;   // o half
    const int ob = oh * 8;      // o base

    float res[2][4][8];
#pragma unroll
    for (int t = 0; t < 2; ++t)
#pragma unroll
        for (int r = 0; r < 4; ++r)
#pragma unroll
            for (int q = 0; q < 8; ++q) res[t][r][q] = 0.0f;

    const float* Wk = W + (size_t)k * (I_CAPS * DIN * DOUT);

#pragma unroll
    for (int c = 0; c < 4; ++c) {          // i-chunks of 32
        __syncthreads();                   // protect previous chunk's readers
        // cooperative stage: 32 x 256 floats -> padded LDS
#pragma unroll
        for (int j = 0; j < 8; ++j) {
            const int e    = j * 1024 + tid * 4;   // [0, 8192)
            const int irow = e >> 8;
            const int rem  = e & 255;
            *reinterpret_cast<float4*>(&wlds[irow * WSTRIDE + rem]) =
                *reinterpret_cast<const float4*>(&Wk[c * 8192 + e]);
        }
        __syncthreads();

        const int i = c * 32 + il;
        // load x rows for both brc (lane pairs l / l^32 read same -> broadcast)
        float xv[2][16];
#pragma unroll
        for (int t = 0; t < 2; ++t) {
            const float* xp = x + ((size_t)(brc0 + t) * I_CAPS + i) * DIN;
#pragma unroll
            for (int q4 = 0; q4 < 4; ++q4) {
                float4 v4 = *reinterpret_cast<const float4*>(&xp[q4 * 4]);
                xv[t][q4 * 4 + 0] = v4.x; xv[t][q4 * 4 + 1] = v4.y;
                xv[t][q4 * 4 + 2] = v4.z; xv[t][q4 * 4 + 3] = v4.w;
            }
        }
        const float* wrow = &wlds[il * WSTRIDE + ob];
#pragma unroll
        for (int d = 0; d < DIN; ++d) {
            float4 wa = *reinterpret_cast<const float4*>(&wrow[d * 16]);
            float4 wb = *reinterpret_cast<const float4*>(&wrow[d * 16 + 4]);
            const float w8[8] = {wa.x, wa.y, wa.z, wa.w, wb.x, wb.y, wb.z, wb.w};
#pragma unroll
            for (int t = 0; t < 2; ++t)
#pragma unroll
                for (int q = 0; q < 8; ++q)
                    res[t][c][q] = fmaf(xv[t][d], w8[q], res[t][c][q]);
        }
    }

    // ---- dynamic routing (3 iterations, last one writes output) ----
#pragma unroll
    for (int t = 0; t < 2; ++t) {
        float bb[4] = {1.0f/128.0f, 1.0f/128.0f, 1.0f/128.0f, 1.0f/128.0f};
        float v[8];
#pragma unroll
        for (int iter = 0; iter < 3; ++iter) {
            // s[o] = sum_i b_i * res[i,o]  (own o-half)
            float s[8];
#pragma unroll
            for (int q = 0; q < 8; ++q) {
                s[q] = bb[0] * res[t][0][q];
#pragma unroll
                for (int r = 1; r < 4; ++r) s[q] = fmaf(bb[r], res[t][r][q], s[q]);
            }
            // reduce over i: butterfly within the 32-lane o-half group
#pragma unroll
            for (int m = 1; m <= 16; m <<= 1) {
#pragma unroll
                for (int q = 0; q < 8; ++q)
                    s[q] += __shfl_xor(s[q], m);
            }
            // squash: sq over all 16 o (combine halves with one xor-32)
            float loc = 0.0f;
#pragma unroll
            for (int q = 0; q < 8; ++q) loc = fmaf(s[q], s[q], loc);
            const float sq = loc + __shfl_xor(loc, 32);
            const float scale = (sq / (1.0f + sq)) / sqrtf(sq + 1e-7f);
#pragma unroll
            for (int q = 0; q < 8; ++q) v[q] = s[q] * scale;

            if (iter < 2) {
                // agreement: b_i += sum_o res[i,o] * v[o]
#pragma unroll
                for (int r = 0; r < 4; ++r) {
                    float tp = 0.0f;
#pragma unroll
                    for (int q = 0; q < 8; ++q) tp = fmaf(res[t][r][q], v[q], tp);
                    bb[r] += tp + __shfl_xor(tp, 32);
                }
            }
        }
        // write: lane 0 of each o-half writes its 8 floats
        if (il == 0) {
            float* op = out + ((size_t)(brc0 + t) * KCAPS + k) * DOUT + ob;
            float4 o0 = {v[0], v[1], v[2], v[3]};
            float4 o1 = {v[4], v[5], v[6], v[7]};
            *reinterpret_cast<float4*>(&op[0]) = o0;
            *reinterpret_cast<float4*>(&op[4]) = o1;
        }
    }
}

extern "C" void kernel_launch(void* const* d_in, const int* in_sizes, int n_in,
                              void* d_out, int out_size, void* d_ws, size_t ws_size,
                              hipStream_t stream) {
    const float* x  = (const float*)d_in[0];
    const float* W  = (const float*)d_in[1];
    float* out      = (float*)d_out;
    hipLaunchKernelGGL(caps_fused, dim3(4096), dim3(256), 0, stream, x, W, out);
}

// Round 2
// 89.009 us; speedup vs baseline: 1.1375x; 1.1375x over previous
//
#include <hip/hip_runtime.h>

// CapsLayer2D, MFMA version.
// dims: brc = B*R*C = 1024, I=128, DIN=16, K=32, DOUT=16.
// inputs: x [1024,128,16] f32; W [32,128,16,16] f32; out [1024,32,16] f32.
//
// Pre-pass: split x,W into bf16 hi/lo and lay them out in MFMA fragment order
// (16x16x32_bf16, K zero-padded to 32 via lanes>=32) in d_ws (12 MB).
// Main: block = 512 thr (8 waves) x 16 brc x 2 k (sequential). Phase A: each
// wave computes res[i][16 brc][16 o] for 16 i via 3 MFMAs (hh + hl + lh),
// stores fp16 to LDS. Phase B: round-1's verified register routing, reading
// res pairs (2 brc packed per b32) from LDS.

using f32x4  = __attribute__((ext_vector_type(4))) float;
using bf16x8 = __attribute__((ext_vector_type(8))) short;
using h16x4  = __attribute__((ext_vector_type(4))) _Float16;
using h16x2  = __attribute__((ext_vector_type(2))) _Float16;

constexpr int I_CAPS = 128;
constexpr int DOUT   = 16;
constexpr int KCAPS  = 32;
constexpr int RS     = 260;  // res_lds row stride (halves): bank step 2, b64-aligned

constexpr size_t XFRAG_N = 64UL * 128 * 32 * 8;  // ushorts per x frag array (4 MB)
constexpr size_t WFRAG_N = 32UL * 128 * 32 * 8;  // ushorts per W frag array (2 MB)
constexpr size_t WS_NEEDED = (2 * XFRAG_N + 2 * WFRAG_N) * sizeof(ushort);  // 12 MB

__device__ inline ushort f2bf(float f) {
    union { float f; uint u; } c{f};
    uint u = c.u;
    return (ushort)((u + 0x7fffu + ((u >> 16) & 1u)) >> 16);   // RNE
}
__device__ inline float bf2f(ushort b) {
    union { uint u; float f; } c{((uint)b) << 16};
    return c.f;
}

// ---------------- pre-pass: build bf16 hi/lo fragment arrays ----------------
__global__ __launch_bounds__(256)
void prepass(const float* __restrict__ x, const float* __restrict__ W,
             ushort* __restrict__ ws) {
    ushort* xh = ws;
    ushort* xl = xh + XFRAG_N;
    ushort* wh = xl + XFRAG_N;
    ushort* wl = wh + WFRAG_N;

    const int tid = blockIdx.x * 256 + threadIdx.x;
    float v[8];
    size_t dst;
    ushort* dh;
    ushort* dl;

    if (tid < 262144) {
        // x job: thread -> (brc, i, h); loads 8 contiguous floats (coalesced)
        const int h = tid & 1, i = (tid >> 1) & 127, brc = tid >> 8;
        const float* p = x + ((size_t)brc * 2048 + i * 16 + 8 * h);
        float4 v0 = *(const float4*)p, v1 = *(const float4*)(p + 4);
        v[0]=v0.x; v[1]=v0.y; v[2]=v0.z; v[3]=v0.w;
        v[4]=v1.x; v[5]=v1.y; v[6]=v1.z; v[7]=v1.w;
        const int tile = brc >> 4, r16 = brc & 15;
        const int l = 16 * h + r16;          // A-frag lane: row=l&15, d=8*(l>>4)+e
        dst = (((size_t)tile * 128 + i) * 32 + l) * 8;
        dh = xh; dl = xl;
    } else if (tid < 262144 + 131072) {
        // W job: thread -> (k, i, lane); B-frag lane: col o=l&15, d=8*(l>>4)+e
        const int t2 = tid - 262144;
        const int l = t2 & 31, i = (t2 >> 5) & 127, k = t2 >> 12;
        const int o = l & 15, dbase = 8 * (l >> 4);
#pragma unroll
        for (int e = 0; e < 8; ++e)
            v[e] = W[(((size_t)k * 128 + i) * 16 + dbase + e) * 16 + o];
        dst = (((size_t)k * 128 + i) * 32 + l) * 8;
        dh = wh; dl = wl;
    } else {
        return;
    }

    uint hp[4], lp[4];
#pragma unroll
    for (int j = 0; j < 4; ++j) {
        ushort h0 = f2bf(v[2*j]),     h1 = f2bf(v[2*j+1]);
        ushort l0 = f2bf(v[2*j]   - bf2f(h0));
        ushort l1 = f2bf(v[2*j+1] - bf2f(h1));
        hp[j] = (uint)h0 | ((uint)h1 << 16);
        lp[j] = (uint)l0 | ((uint)l1 << 16);
    }
    *(uint4*)(dh + dst) = make_uint4(hp[0], hp[1], hp[2], hp[3]);
    *(uint4*)(dl + dst) = make_uint4(lp[0], lp[1], lp[2], lp[3]);
}

// ---------------- main: MFMA predictions + register routing ----------------
__global__ __launch_bounds__(512, 4)
void caps_mfma(const ushort* __restrict__ ws, float* __restrict__ out) {
    __shared__ _Float16 res_lds[128 * RS];   // 66,560 B -> 2 blocks/CU
    const ushort* xh = ws;
    const ushort* xl = xh + XFRAG_N;
    const ushort* wh = xl + XFRAG_N;
    const ushort* wl = wh + WFRAG_N;

    const int tid  = threadIdx.x;
    const int lane = tid & 63;
    const int w    = tid >> 6;              // wave 0..7
    const int kpair = blockIdx.x >> 6;      // 0..15
    const int tile  = blockIdx.x & 63;      // 0..63  (consecutive blocks share k)

    const int il = lane & 31;
    const int oh = lane >> 5;

    const int o16 = lane & 15;              // phase-A MFMA C col (o)
    const int bq  = lane >> 4;              // phase-A C row group (brc base /4)
    const bool lo32 = (lane < 32);

    for (int kk = 0; kk < 2; ++kk) {
        const int k = kpair * 2 + kk;
        if (kk) __syncthreads();            // res_lds reuse: readers done

        // ---- phase A: res[i][o][brc] -> LDS (fp16) ----
        {
            const size_t xbase = (size_t)tile * 128 * 32 * 8;
            const size_t wbase = (size_t)k    * 128 * 32 * 8;
#pragma unroll 2
            for (int ii = 0; ii < 16; ++ii) {
                const int i = w * 16 + ii;
                bf16x8 ah{}, al{}, bh{}, bl{};
                if (lo32) {
                    const size_t fo = ((size_t)i * 32 + lane) * 8;
                    ah = *(const bf16x8*)(xh + xbase + fo);
                    al = *(const bf16x8*)(xl + xbase + fo);
                    bh = *(const bf16x8*)(wh + wbase + fo);
                    bl = *(const bf16x8*)(wl + wbase + fo);
                }
                f32x4 acc = {0.f, 0.f, 0.f, 0.f};
                acc = __builtin_amdgcn_mfma_f32_16x16x32_bf16(ah, bh, acc, 0, 0, 0);
                acc = __builtin_amdgcn_mfma_f32_16x16x32_bf16(ah, bl, acc, 0, 0, 0);
                acc = __builtin_amdgcn_mfma_f32_16x16x32_bf16(al, bh, acc, 0, 0, 0);
                // C layout: col=lane&15 (o), row=(lane>>4)*4+reg (brc)
                h16x4 hv = {(_Float16)acc[0], (_Float16)acc[1],
                            (_Float16)acc[2], (_Float16)acc[3]};
                *(h16x4*)&res_lds[i * RS + o16 * 16 + bq * 4] = hv;
            }
        }
        __syncthreads();

        // ---- phase B: load res pairs (brc 2w, 2w+1) and route in registers ----
        float res[2][4][8];
#pragma unroll
        for (int r = 0; r < 4; ++r) {
            const int i = r * 32 + il;
#pragma unroll
            for (int q = 0; q < 8; ++q) {
                const int o = oh * 8 + q;
                h16x2 hv = *(const h16x2*)&res_lds[i * RS + o * 16 + 2 * w];
                res[0][r][q] = (float)hv[0];
                res[1][r][q] = (float)hv[1];
            }
        }

#pragma unroll
        for (int t = 0; t < 2; ++t) {
            float bb[4] = {0.0078125f, 0.0078125f, 0.0078125f, 0.0078125f};
            float v[8];
#pragma unroll
            for (int iter = 0; iter < 3; ++iter) {
                float s[8];
#pragma unroll
                for (int q = 0; q < 8; ++q) {
                    s[q] = bb[0] * res[t][0][q];
#pragma unroll
                    for (int r = 1; r < 4; ++r) s[q] = fmaf(bb[r], res[t][r][q], s[q]);
                }
#pragma unroll
                for (int m = 1; m <= 16; m <<= 1)
#pragma unroll
                    for (int q = 0; q < 8; ++q) s[q] += __shfl_xor(s[q], m);
                float loc = 0.f;
#pragma unroll
                for (int q = 0; q < 8; ++q) loc = fmaf(s[q], s[q], loc);
                const float sq = loc + __shfl_xor(loc, 32);
                const float scale = (sq / (1.f + sq)) / sqrtf(sq + 1e-7f);
#pragma unroll
                for (int q = 0; q < 8; ++q) v[q] = s[q] * scale;
                if (iter < 2) {
#pragma unroll
                    for (int r = 0; r < 4; ++r) {
                        float tp = 0.f;
#pragma unroll
                        for (int q = 0; q < 8; ++q) tp = fmaf(res[t][r][q], v[q], tp);
                        bb[r] += tp + __shfl_xor(tp, 32);
                    }
                }
            }
            if (il == 0) {
                const int brcg = tile * 16 + 2 * w + t;
                float* op = out + ((size_t)brcg * KCAPS + k) * DOUT + oh * 8;
                *(float4*)(op)     = make_float4(v[0], v[1], v[2], v[3]);
                *(float4*)(op + 4) = make_float4(v[4], v[5], v[6], v[7]);
            }
        }
    }
}

// ---------------- fallback (round-1 fp32 kernel) if ws too small ----------------
constexpr int WSTRIDE = 260;

__global__ __launch_bounds__(256)
void caps_fused(const float* __restrict__ x,
                const float* __restrict__ W,
                float* __restrict__ out)
{
    __shared__ float wlds[32 * WSTRIDE];

    const int tid  = threadIdx.x;
    const int lane = tid & 63;
    const int wave = tid >> 6;

    const int b    = blockIdx.x;
    const int tq   = b & 15;
    const int kq   = (b >> 4) & 7;
    const int sg   = b >> 7;
    const int k    = (sg & 3) * 8 + kq;
    const int tile = (sg >> 2) * 16 + tq;

    const int brc0 = tile * 8 + wave * 2;
    const int il = lane & 31;
    const int oh = lane >> 5;
    const int ob = oh * 8;

    float res[2][4][8];
#pragma unroll
    for (int t = 0; t < 2; ++t)
#pragma unroll
        for (int r = 0; r < 4; ++r)
#pragma unroll
            for (int q = 0; q < 8; ++q) res[t][r][q] = 0.0f;

    const float* Wk = W + (size_t)k * (I_CAPS * 16 * DOUT);

#pragma unroll
    for (int c = 0; c < 4; ++c) {
        __syncthreads();
#pragma unroll
        for (int j = 0; j < 8; ++j) {
            const int e    = j * 1024 + tid * 4;
            const int irow = e >> 8;
            const int rem  = e & 255;
            *reinterpret_cast<float4*>(&wlds[irow * WSTRIDE + rem]) =
                *reinterpret_cast<const float4*>(&Wk[c * 8192 + e]);
        }
        __syncthreads();

        const int i = c * 32 + il;
        float xv[2][16];
#pragma unroll
        for (int t = 0; t < 2; ++t) {
            const float* xp = x + ((size_t)(brc0 + t) * I_CAPS + i) * 16;
#pragma unroll
            for (int q4 = 0; q4 < 4; ++q4) {
                float4 v4 = *reinterpret_cast<const float4*>(&xp[q4 * 4]);
                xv[t][q4*4+0] = v4.x; xv[t][q4*4+1] = v4.y;
                xv[t][q4*4+2] = v4.z; xv[t][q4*4+3] = v4.w;
            }
        }
        const float* wrow = &wlds[il * WSTRIDE + ob];
#pragma unroll
        for (int d = 0; d < 16; ++d) {
            float4 wa = *reinterpret_cast<const float4*>(&wrow[d * 16]);
            float4 wb = *reinterpret_cast<const float4*>(&wrow[d * 16 + 4]);
            const float w8[8] = {wa.x, wa.y, wa.z, wa.w, wb.x, wb.y, wb.z, wb.w};
#pragma unroll
            for (int t = 0; t < 2; ++t)
#pragma unroll
                for (int q = 0; q < 8; ++q)
                    res[t][c][q] = fmaf(xv[t][d], w8[q], res[t][c][q]);
        }
    }

#pragma unroll
    for (int t = 0; t < 2; ++t) {
        float bb[4] = {1.0f/128.0f, 1.0f/128.0f, 1.0f/128.0f, 1.0f/128.0f};
        float v[8];
#pragma unroll
        for (int iter = 0; iter < 3; ++iter) {
            float s[8];
#pragma unroll
            for (int q = 0; q < 8; ++q) {
                s[q] = bb[0] * res[t][0][q];
#pragma unroll
                for (int r = 1; r < 4; ++r) s[q] = fmaf(bb[r], res[t][r][q], s[q]);
            }
#pragma unroll
            for (int m = 1; m <= 16; m <<= 1)
#pragma unroll
                for (int q = 0; q < 8; ++q) s[q] += __shfl_xor(s[q], m);
            float loc = 0.0f;
#pragma unroll
            for (int q = 0; q < 8; ++q) loc = fmaf(s[q], s[q], loc);
            const float sq = loc + __shfl_xor(loc, 32);
            const float scale = (sq / (1.0f + sq)) / sqrtf(sq + 1e-7f);
#pragma unroll
            for (int q = 0; q < 8; ++q) v[q] = s[q] * scale;
            if (iter < 2) {
#pragma unroll
                for (int r = 0; r < 4; ++r) {
                    float tp = 0.0f;
#pragma unroll
                    for (int q = 0; q < 8; ++q) tp = fmaf(res[t][r][q], v[q], tp);
                    bb[r] += tp + __shfl_xor(tp, 32);
                }
            }
        }
        if (il == 0) {
            float* op = out + ((size_t)(brc0 + t) * KCAPS + k) * DOUT + ob;
            *reinterpret_cast<float4*>(&op[0]) = make_float4(v[0], v[1], v[2], v[3]);
            *reinterpret_cast<float4*>(&op[4]) = make_float4(v[4], v[5], v[6], v[7]);
        }
    }
}

extern "C" void kernel_launch(void* const* d_in, const int* in_sizes, int n_in,
                              void* d_out, int out_size, void* d_ws, size_t ws_size,
                              hipStream_t stream) {
    const float* x  = (const float*)d_in[0];
    const float* W  = (const float*)d_in[1];
    float* out      = (float*)d_out;
    if (ws_size >= WS_NEEDED && d_ws != nullptr) {
        ushort* ws = (ushort*)d_ws;
        hipLaunchKernelGGL(prepass,   dim3(1536), dim3(256), 0, stream, x, W, ws);
        hipLaunchKernelGGL(caps_mfma, dim3(1024), dim3(512), 0, stream, ws, out);
    } else {
        hipLaunchKernelGGL(caps_fused, dim3(4096), dim3(256), 0, stream, x, W, out);
    }
}